// Round 8
// baseline (326.859 us; speedup 1.0000x reference)
//
#include <hip/hip_runtime.h>
#include <cstddef>
#include <cstdint>

// Problem constants (all powers of two).
#define B_    128
#define IN_   256
#define OUT_  256
#define HS_   512

#define NTHR_  512
#define NBLK_  1024   // 8 sibling blocks per sample, 64 rows each

__device__ __forceinline__ float clip1(float x) {
    return fminf(fmaxf(x, -1.f), 1.f);
}

typedef float f32x4 __attribute__((ext_vector_type(4)));
__device__ __forceinline__ void nt_store4(float4* p, float4 v) {
    // nontemporal: hebb_new is write-once, never re-read -> don't pollute
    // L2/L3 (which must keep holding hebb for the pass-2 re-read).
    __builtin_nontemporal_store(*(f32x4*)&v, (f32x4*)p);
}

// ---------------------------------------------------------------------------
// k0_pre: pre[b,i] = i2h_b[i] + inputs[b]·i2h_w[i] + hidden[b]·w[i]
// The sample-SHARED part of the recurrent pre-activation, done as a real
// tiled GEMM so w/i2h_w are read ~once (not once per sample as in pass1
// before this round). 34 MFLOP -> a few µs. Tiles: 32 i x 32 b, K=768
// (hidden:512 then inputs:256) staged in 64-chunks. Grid 64 blocks x 256.
// ---------------------------------------------------------------------------
__global__ __launch_bounds__(256) void k0_pre(
    const float* __restrict__ inputs,   // [B, IN]
    const float* __restrict__ hidden,   // [B, HS]
    const float* __restrict__ i2h_w,    // [HS, IN]
    const float* __restrict__ i2h_b,    // [HS]
    const float* __restrict__ w,        // [HS, HS]
    float* __restrict__ pre)            // [B, HS] (workspace)
{
    const int it  = blockIdx.x & 15;    // i tile (16 tiles of 32)
    const int bt  = blockIdx.x >> 4;    // b tile (4 tiles of 32)
    const int tid = threadIdx.x;
    const int il  = tid & 31;           // local i
    const int bg  = tid >> 5;           // b group 0..7 (each covers 4 b)

    __shared__ float Xl[32][68];        // [b_local][k], pad 68: 16B-aligned
    __shared__ float Wl[32][68];        // [i_local][k]

    float acc0 = 0.f, acc1 = 0.f, acc2 = 0.f, acc3 = 0.f;

    for (int ck = 0; ck < 12; ++ck) {
        __syncthreads();
        #pragma unroll
        for (int r = 0; r < 2; ++r) {
            const int f   = tid + 256 * r;   // 0..511
            const int row = f >> 4;          // 0..31
            const int kf  = f & 15;          // float4 within the 64-chunk
            float4 xv, wv;
            if (ck < 8) {
                xv = *(const float4*)(hidden + (size_t)(bt*32 + row)*HS_ + ck*64 + kf*4);
                wv = *(const float4*)(w      + (size_t)(it*32 + row)*HS_ + ck*64 + kf*4);
            } else {
                xv = *(const float4*)(inputs + (size_t)(bt*32 + row)*IN_ + (ck-8)*64 + kf*4);
                wv = *(const float4*)(i2h_w  + (size_t)(it*32 + row)*IN_ + (ck-8)*64 + kf*4);
            }
            *(float4*)&Xl[row][kf*4] = xv;
            *(float4*)&Wl[row][kf*4] = wv;
        }
        __syncthreads();
        #pragma unroll
        for (int kk = 0; kk < 64; ++kk) {
            const float wv = Wl[il][kk];
            acc0 = fmaf(wv, Xl[bg     ][kk], acc0);
            acc1 = fmaf(wv, Xl[bg +  8][kk], acc1);
            acc2 = fmaf(wv, Xl[bg + 16][kk], acc2);
            acc3 = fmaf(wv, Xl[bg + 24][kk], acc3);
        }
    }

    const int i = it * 32 + il;
    const float bias = i2h_b[i];
    pre[(size_t)(bt*32 + bg     ) * HS_ + i] = acc0 + bias;
    pre[(size_t)(bt*32 + bg +  8) * HS_ + i] = acc1 + bias;
    pre[(size_t)(bt*32 + bg + 16) * HS_ + i] = acc2 + bias;
    pre[(size_t)(bt*32 + bg + 24) * HS_ + i] = acc3 + bias;
}

// ---------------------------------------------------------------------------
// Pass 1 (slim): hactiv + da/value partials. 1024 blocks x 512 threads =
// 4 blocks/CU = 32 waves/CU (64 VGPR; round-5/6 verified).
// Per 2-row iteration: only 8 float4 loads (hebb + alpha) + 32 FMA --
// the w/i2h work lives in k0_pre. Load traffic 454 -> 266 MB.
// ---------------------------------------------------------------------------
__global__ __launch_bounds__(NTHR_, 4) void k_pass1_slim(
    const float* __restrict__ hidden,   // [B, HS]
    const float* __restrict__ hebb,     // [B, HS, HS]
    const float* __restrict__ alpha,    // [HS, HS]
    const float* __restrict__ pre,      // [B, HS] (from k0_pre)
    const float* __restrict__ h2v_w,    // [HS]
    const float* __restrict__ h2da_w,   // [HS]
    float* __restrict__ hactiv,         // [B, HS]
    float* __restrict__ ws_pd,          // [B*8] da partials (plain stores)
    float* __restrict__ ws_pv)          // [B*8] value partials
{
    const int blk  = blockIdx.x;
    const int b    = blk >> 3;          // sample
    const int s    = blk & 7;           // sibling 0..7
    const int tid  = threadIdx.x;
    const int wave = tid >> 6;          // 0..7
    const int lane = tid & 63;
    const int r0   = s * 64 + wave * 8; // first row of this wave's strip

    __shared__ float s_pd[8], s_pv[8];

    const float4* hid4 = (const float4*)(hidden + (size_t)b * HS_);
    const float4 h0 = hid4[lane];
    const float4 h1 = hid4[lane + 64];

    const float4* hb4 = (const float4*)hebb + ((size_t)b * HS_) * (HS_ / 4);
    const float4* a4  = (const float4*)alpha;

    float pd = 0.f, pv = 0.f;
    for (int t = 0; t < 8; t += 2) {
        const int i = r0 + t;
        const float4* hpA = hb4 + (size_t)i * (HS_ / 4);
        const float4* apA = a4  + (size_t)i * (HS_ / 4);

        // 8 independent float4 loads
        const float4 xA0 = hpA[lane],        xA1 = hpA[lane + 64];
        const float4 xB0 = hpA[128 + lane],  xB1 = hpA[128 + lane + 64];
        const float4 aA0 = apA[lane],        aA1 = apA[lane + 64];
        const float4 aB0 = apA[128 + lane],  aB1 = apA[128 + lane + 64];

        float a, c;
        a  = (aA0.x * xA0.x) * h0.x;
        a += (aA0.y * xA0.y) * h0.y;
        a += (aA0.z * xA0.z) * h0.z;
        a += (aA0.w * xA0.w) * h0.w;
        a += (aA1.x * xA1.x) * h1.x;
        a += (aA1.y * xA1.y) * h1.y;
        a += (aA1.z * xA1.z) * h1.z;
        a += (aA1.w * xA1.w) * h1.w;

        c  = (aB0.x * xB0.x) * h0.x;
        c += (aB0.y * xB0.y) * h0.y;
        c += (aB0.z * xB0.z) * h0.z;
        c += (aB0.w * xB0.w) * h0.w;
        c += (aB1.x * xB1.x) * h1.x;
        c += (aB1.y * xB1.y) * h1.y;
        c += (aB1.z * xB1.z) * h1.z;
        c += (aB1.w * xB1.w) * h1.w;

        #pragma unroll
        for (int off = 1; off < 64; off <<= 1) {
            a += __shfl_xor(a, off, 64);
            c += __shfl_xor(c, off, 64);
        }

        const float hA = tanhf(a + pre[(size_t)b * HS_ + i]);
        const float hB = tanhf(c + pre[(size_t)b * HS_ + i + 1]);
        if (lane == 0) {
            float2* hp = (float2*)(hactiv + (size_t)b * HS_ + i);
            *hp = make_float2(hA, hB);
            pd += hA * h2da_w[i] + hB * h2da_w[i + 1];
            pv += hA * h2v_w[i]  + hB * h2v_w[i + 1];
        }
    }

    if (lane == 0) { s_pd[wave] = pd; s_pv[wave] = pv; }
    __syncthreads();
    if (tid == 0) {
        float sd = 0.f, sv = 0.f;
        #pragma unroll
        for (int k = 0; k < 8; ++k) { sd += s_pd[k]; sv += s_pv[k]; }
        ws_pd[b * 8 + s] = sd;      // plain store; kernel boundary = sync
        ws_pv[b * 8 + s] = sv;
    }
}

// ---------------------------------------------------------------------------
// Pass 1 (full, round-6 version): used when workspace can't hold `pre`.
// ---------------------------------------------------------------------------
__global__ __launch_bounds__(NTHR_, 4) void k_pass1_full(
    const float* __restrict__ inputs, const float* __restrict__ hidden,
    const float* __restrict__ hebb, const float* __restrict__ i2h_w,
    const float* __restrict__ i2h_b, const float* __restrict__ w,
    const float* __restrict__ alpha, const float* __restrict__ h2v_w,
    const float* __restrict__ h2da_w, float* __restrict__ hactiv,
    float* __restrict__ ws_pd, float* __restrict__ ws_pv)
{
    const int blk  = blockIdx.x;
    const int b    = blk >> 3;
    const int s    = blk & 7;
    const int tid  = threadIdx.x;
    const int wave = tid >> 6;
    const int lane = tid & 63;
    const int r0   = s * 64 + wave * 8;

    __shared__ float s_pd[8], s_pv[8];

    const float4* hid4 = (const float4*)(hidden + (size_t)b * HS_);
    const float4 h0  = hid4[lane];
    const float4 h1  = hid4[lane + 64];
    const float4 in4 = ((const float4*)(inputs + (size_t)b * IN_))[lane];

    const float4* hb4 = (const float4*)hebb + ((size_t)b * HS_) * (HS_ / 4);
    const float4* w4  = (const float4*)w;
    const float4* a4  = (const float4*)alpha;
    const float4* iw4 = (const float4*)i2h_w;

    float pd = 0.f, pv = 0.f;
    for (int t = 0; t < 8; t += 2) {
        const int i = r0 + t;
        const float4* hpA = hb4 + (size_t)i * (HS_ / 4);
        const float4* hpB = hpA + (HS_ / 4);
        const float4* wpA = w4  + (size_t)i * (HS_ / 4);
        const float4* apA = a4  + (size_t)i * (HS_ / 4);
        const float4* ipA = iw4 + (size_t)i * (IN_ / 4);

        const float4 xA0 = hpA[lane],            xA1 = hpA[lane + 64];
        const float4 xB0 = hpB[lane],            xB1 = hpB[lane + 64];
        const float4 wA0 = wpA[lane],            wA1 = wpA[lane + 64];
        const float4 wB0 = wpA[128 + lane],      wB1 = wpA[128 + lane + 64];
        const float4 aA0 = apA[lane],            aA1 = apA[lane + 64];
        const float4 aB0 = apA[128 + lane],      aB1 = apA[128 + lane + 64];
        const float4 iA  = ipA[lane];
        const float4 iB  = ipA[64 + lane];

        float a, c;
        a  = (wA0.x + aA0.x * xA0.x) * h0.x;
        a += (wA0.y + aA0.y * xA0.y) * h0.y;
        a += (wA0.z + aA0.z * xA0.z) * h0.z;
        a += (wA0.w + aA0.w * xA0.w) * h0.w;
        a += (wA1.x + aA1.x * xA1.x) * h1.x;
        a += (wA1.y + aA1.y * xA1.y) * h1.y;
        a += (wA1.z + aA1.z * xA1.z) * h1.z;
        a += (wA1.w + aA1.w * xA1.w) * h1.w;
        a += iA.x * in4.x + iA.y * in4.y + iA.z * in4.z + iA.w * in4.w;

        c  = (wB0.x + aB0.x * xB0.x) * h0.x;
        c += (wB0.y + aB0.y * xB0.y) * h0.y;
        c += (wB0.z + aB0.z * xB0.z) * h0.z;
        c += (wB0.w + aB0.w * xB0.w) * h0.w;
        c += (wB1.x + aB1.x * xB1.x) * h1.x;
        c += (wB1.y + aB1.y * xB1.y) * h1.y;
        c += (wB1.z + aB1.z * xB1.z) * h1.z;
        c += (wB1.w + aB1.w * xB1.w) * h1.w;
        c += iB.x * in4.x + iB.y * in4.y + iB.z * in4.z + iB.w * in4.w;

        #pragma unroll
        for (int off = 1; off < 64; off <<= 1) {
            a += __shfl_xor(a, off, 64);
            c += __shfl_xor(c, off, 64);
        }

        const float hA = tanhf(a + i2h_b[i]);
        const float hB = tanhf(c + i2h_b[i + 1]);
        if (lane == 0) {
            float2* hp = (float2*)(hactiv + (size_t)b * HS_ + i);
            *hp = make_float2(hA, hB);
            pd += hA * h2da_w[i] + hB * h2da_w[i + 1];
            pv += hA * h2v_w[i]  + hB * h2v_w[i + 1];
        }
    }

    if (lane == 0) { s_pd[wave] = pd; s_pv[wave] = pv; }
    __syncthreads();
    if (tid == 0) {
        float sd = 0.f, sv = 0.f;
        #pragma unroll
        for (int k = 0; k < 8; ++k) { sd += s_pd[k]; sv += s_pv[k]; }
        ws_pd[b * 8 + s] = sd;
        ws_pv[b * 8 + s] = sv;
    }
}

// ---------------------------------------------------------------------------
// Pass 2: hebb update + heads. Round-8 startup fix: da is computed PER
// THREAD from the 8 broadcast partials (no tid-0 + barrier on the critical
// path), per-wave hactiv scalars live in registers, and the s_h staging for
// the activout head is deferred until after the hebb stream -> the 268 MB
// R+W stream starts issuing at cycle ~0.
// ---------------------------------------------------------------------------
__global__ __launch_bounds__(NTHR_, 4) void k_pass2(
    const float* __restrict__ hidden,   // [B, HS]
    const float* __restrict__ hebb,     // [B, HS, HS]
    const float* __restrict__ h2o_w,    // [OUT, HS]
    const float* __restrict__ h2o_b,    // [OUT]
    const float* __restrict__ h2v_b,    // [1]
    const float* __restrict__ h2da_b,   // [1]
    const float* __restrict__ hactiv,   // [B, HS]
    float* __restrict__ activout,       // [B, OUT]
    float* __restrict__ valueout,       // [B]
    float* __restrict__ hebb_new,       // [B, HS, HS]
    const float* __restrict__ ws_pd,    // [B*8]
    const float* __restrict__ ws_pv)    // [B*8]
{
    const int blk  = blockIdx.x;
    const int b    = blk >> 3;
    const int s    = blk & 7;
    const int tid  = threadIdx.x;
    const int lane = tid & 63;
    const int wave = tid >> 6;
    const int r0   = s * 64 + wave * 8;

    __shared__ float s_h[HS_];
    __shared__ float s_part[512];

    // da/value: every thread sums the 8 broadcast partials (no barrier).
    float sd = 0.f, sv = 0.f;
    #pragma unroll
    for (int k = 0; k < 8; ++k) {
        sd += ws_pd[b * 8 + k];
        sv += ws_pv[b * 8 + k];
    }
    const float da_b = tanhf(sd + h2da_b[0]);
    if (s == 0 && tid == 0)
        valueout[b] = sv + h2v_b[0];

    // per-wave hactiv scalars (uniform broadcast loads)
    float hr[8];
    #pragma unroll
    for (int q = 0; q < 8; ++q)
        hr[q] = hactiv[(size_t)b * HS_ + r0 + q];

    const float4* hid4 = (const float4*)(hidden + (size_t)b * HS_);
    const float4 h0 = hid4[lane];
    const float4 h1 = hid4[lane + 64];

    const float4* hb4 = (const float4*)hebb + ((size_t)b * HS_) * (HS_ / 4);

    for (int t = 0; t < 8; t += 2) {
        const int i = r0 + t;
        const float4* xp = hb4 + (size_t)i * (HS_ / 4);
        const float4 x0 = xp[lane],       x1 = xp[lane + 64];
        const float4 y0 = xp[128 + lane], y1 = xp[128 + lane + 64];
        const float scA = da_b * hr[t];
        const float scB = da_b * hr[t + 1];

        float4 o0, o1, p0, p1;
        o0.x = clip1(fmaf(scA, h0.x, x0.x));
        o0.y = clip1(fmaf(scA, h0.y, x0.y));
        o0.z = clip1(fmaf(scA, h0.z, x0.z));
        o0.w = clip1(fmaf(scA, h0.w, x0.w));
        o1.x = clip1(fmaf(scA, h1.x, x1.x));
        o1.y = clip1(fmaf(scA, h1.y, x1.y));
        o1.z = clip1(fmaf(scA, h1.z, x1.z));
        o1.w = clip1(fmaf(scA, h1.w, x1.w));
        p0.x = clip1(fmaf(scB, h0.x, y0.x));
        p0.y = clip1(fmaf(scB, h0.y, y0.y));
        p0.z = clip1(fmaf(scB, h0.z, y0.z));
        p0.w = clip1(fmaf(scB, h0.w, y0.w));
        p1.x = clip1(fmaf(scB, h1.x, y1.x));
        p1.y = clip1(fmaf(scB, h1.y, y1.y));
        p1.z = clip1(fmaf(scB, h1.z, y1.z));
        p1.w = clip1(fmaf(scB, h1.w, y1.w));

        float4* dp = (float4*)hebb_new + ((size_t)b * HS_ + i) * (HS_ / 4);
        nt_store4(dp + lane,            o0);
        nt_store4(dp + lane + 64,       o1);
        nt_store4(dp + 128 + lane,      p0);
        nt_store4(dp + 128 + lane + 64, p1);
    }

    // ---- head: stage hactiv[b] now, then this block's 32 outputs ---------
    if (tid < 128)
        ((float4*)s_h)[tid] = ((const float4*)(hactiv + (size_t)b * HS_))[tid];
    __syncthreads();

    {
        const int ol = tid & 31;
        const int sg = tid >> 5;            // 0..15 dot-segment
        const int o  = s * 32 + ol;
        const float4* wp  = (const float4*)(h2o_w + (size_t)o * HS_);
        const float4* hp4 = (const float4*)s_h;
        float acc = 0.f;
        #pragma unroll
        for (int c2 = 0; c2 < 8; ++c2) {
            const float4 wv = wp[sg * 8 + c2];
            const float4 hv = hp4[sg * 8 + c2];
            acc += wv.x * hv.x + wv.y * hv.y + wv.z * hv.z + wv.w * hv.w;
        }
        s_part[sg * 32 + ol] = acc;
    }
    __syncthreads();
    if (tid < 32) {
        const int o = s * 32 + tid;
        float acc = h2o_b[o];
        #pragma unroll
        for (int k = 0; k < 16; ++k)
            acc += s_part[k * 32 + tid];
        activout[(size_t)b * OUT_ + o] = acc;
    }
}

// ---------------------------------------------------------------------------
// Legacy fallback (original verified 3-kernel version) — tiny workspace only.
// ---------------------------------------------------------------------------
__global__ __launch_bounds__(256) void k1_hactiv(
    const float* __restrict__ inputs, const float* __restrict__ hidden,
    const float* __restrict__ hebb, const float* __restrict__ i2h_w,
    const float* __restrict__ i2h_b, const float* __restrict__ w,
    const float* __restrict__ alpha, float* __restrict__ hactiv)
{
    const int b     = blockIdx.x & (B_ - 1);
    const int chunk = blockIdx.x >> 7;
    const int tid   = threadIdx.x;
    const int wave  = tid >> 6;
    const int lane  = tid & 63;

    const float4* hid4 = (const float4*)(hidden + (size_t)b * HS_);
    const float4  h0   = hid4[lane];
    const float4  h1   = hid4[lane + 64];
    const float4  in4  = ((const float4*)(inputs + (size_t)b * IN_))[lane];

    const int i0 = chunk * 64 + wave * 16;

    for (int r = 0; r < 16; ++r) {
        const int i = i0 + r;
        const float4* hb = (const float4*)(hebb + ((size_t)b * HS_ + i) * HS_);
        const float4* wr = (const float4*)(w     + (size_t)i * HS_);
        const float4* ar = (const float4*)(alpha + (size_t)i * HS_);

        const float4 hb0 = hb[lane];
        const float4 hb1 = hb[lane + 64];
        const float4 wv0 = wr[lane];
        const float4 wv1 = wr[lane + 64];
        const float4 av0 = ar[lane];
        const float4 av1 = ar[lane + 64];
        const float4 iw  = ((const float4*)(i2h_w + (size_t)i * IN_))[lane];

        float acc;
        acc  = (wv0.x + av0.x * hb0.x) * h0.x;
        acc += (wv0.y + av0.y * hb0.y) * h0.y;
        acc += (wv0.z + av0.z * hb0.z) * h0.z;
        acc += (wv0.w + av0.w * hb0.w) * h0.w;
        acc += (wv1.x + av1.x * hb1.x) * h1.x;
        acc += (wv1.y + av1.y * hb1.y) * h1.y;
        acc += (wv1.z + av1.z * hb1.z) * h1.z;
        acc += (wv1.w + av1.w * hb1.w) * h1.w;
        acc += iw.x * in4.x + iw.y * in4.y + iw.z * in4.z + iw.w * in4.w;

        #pragma unroll
        for (int off = 32; off > 0; off >>= 1)
            acc += __shfl_down(acc, off, 64);

        if (lane == 0)
            hactiv[(size_t)b * HS_ + i] = tanhf(acc + i2h_b[i]);
    }
}

__global__ __launch_bounds__(256) void k2_heads(
    const float* __restrict__ hactiv, const float* __restrict__ h2o_w,
    const float* __restrict__ h2o_b, const float* __restrict__ h2v_w,
    const float* __restrict__ h2v_b, const float* __restrict__ h2da_w,
    const float* __restrict__ h2da_b, float* __restrict__ activout,
    float* __restrict__ valueout, float* __restrict__ da)
{
    const int b   = blockIdx.x;
    const int tid = threadIdx.x;

    __shared__ float s_h[HS_];
    __shared__ float red_v[256];
    __shared__ float red_d[256];

    for (int t = tid; t < HS_; t += 256)
        s_h[t] = hactiv[(size_t)b * HS_ + t];
    __syncthreads();

    const float4* wr  = (const float4*)(h2o_w + (size_t)tid * HS_);
    const float4* sh4 = (const float4*)s_h;
    float acc = 0.f;
    #pragma unroll 4
    for (int q = 0; q < HS_ / 4; ++q) {
        const float4 wv = wr[q];
        const float4 hv = sh4[q];
        acc += wv.x * hv.x + wv.y * hv.y + wv.z * hv.z + wv.w * hv.w;
    }
    activout[(size_t)b * OUT_ + tid] = acc + h2o_b[tid];

    float pv = 0.f, pd = 0.f;
    for (int t = tid; t < HS_; t += 256) {
        const float hv = s_h[t];
        pv += hv * h2v_w[t];
        pd += hv * h2da_w[t];
    }
    red_v[tid] = pv;
    red_d[tid] = pd;
    __syncthreads();
    for (int s2 = 128; s2 > 0; s2 >>= 1) {
        if (tid < s2) {
            red_v[tid] += red_v[tid + s2];
            red_d[tid] += red_d[tid + s2];
        }
        __syncthreads();
    }
    if (tid == 0) {
        valueout[b] = red_v[0] + h2v_b[0];
        da[b]       = tanhf(red_d[0] + h2da_b[0]);
    }
}

__global__ __launch_bounds__(256) void k3_hebb(
    const float* __restrict__ hebb, const float* __restrict__ hidden,
    const float* __restrict__ hactiv, const float* __restrict__ da,
    float* __restrict__ hebb_new)
{
    const int tid = threadIdx.x;
    const size_t base = (size_t)blockIdx.x * 1024;

    #pragma unroll
    for (int k = 0; k < 4; ++k) {
        const size_t idx = base + (size_t)k * 256 + tid;
        const int j4  = (int)(idx & 127);
        const int row = (int)(idx >> 7);
        const int i   = row & (HS_ - 1);
        const int b   = row >> 9;

        const float scale = da[b] * hactiv[(size_t)b * HS_ + i];
        const float4 hv = ((const float4*)hebb)[idx];
        const float4 hd = ((const float4*)hidden)[(size_t)b * (HS_ / 4) + j4];

        float4 r;
        r.x = fminf(fmaxf(fmaf(scale, hd.x, hv.x), -1.f), 1.f);
        r.y = fminf(fmaxf(fmaf(scale, hd.y, hv.y), -1.f), 1.f);
        r.z = fminf(fmaxf(fmaf(scale, hd.z, hv.z), -1.f), 1.f);
        r.w = fminf(fmaxf(fmaf(scale, hd.w, hv.w), -1.f), 1.f);
        ((float4*)hebb_new)[idx] = r;
    }
}

// ---------------------------------------------------------------------------
extern "C" void kernel_launch(void* const* d_in, const int* in_sizes, int n_in,
                              void* d_out, int out_size, void* d_ws, size_t ws_size,
                              hipStream_t stream)
{
    const float* inputs = (const float*)d_in[0];
    const float* hidden = (const float*)d_in[1];
    const float* hebb   = (const float*)d_in[2];
    const float* i2h_w  = (const float*)d_in[3];
    const float* i2h_b  = (const float*)d_in[4];
    const float* w      = (const float*)d_in[5];
    const float* alpha  = (const float*)d_in[6];
    const float* h2o_w  = (const float*)d_in[7];
    const float* h2o_b  = (const float*)d_in[8];
    const float* h2v_w  = (const float*)d_in[9];
    const float* h2v_b  = (const float*)d_in[10];
    const float* h2da_w = (const float*)d_in[11];
    const float* h2da_b = (const float*)d_in[12];

    float* out = (float*)d_out;
    // Output layout (flat, return order): activout | valueout | hactiv | hebb_new
    float* activout = out;                              // 128*256   = 32768
    float* valueout = out + 32768;                      // 128
    float* hactiv   = out + 32768 + 128;                // 128*512   = 65536
    float* hebb_new = out + 32768 + 128 + 65536;        // 128*512*512

    const size_t part_bytes = (size_t)(2 * B_ * 8) * sizeof(float);       // 8 KB
    const size_t big_bytes  = part_bytes + (size_t)(B_ * HS_) * sizeof(float); // +256 KB

    if (ws_size >= big_bytes) {
        float* ws_pd = (float*)d_ws;                    // [128*8]
        float* ws_pv = ws_pd + B_ * 8;                  // [128*8]
        float* pre   = ws_pv + B_ * 8;                  // [128*512]

        k0_pre<<<dim3(64), dim3(256), 0, stream>>>(
            inputs, hidden, i2h_w, i2h_b, w, pre);

        k_pass1_slim<<<dim3(NBLK_), dim3(NTHR_), 0, stream>>>(
            hidden, hebb, alpha, pre, h2v_w, h2da_w, hactiv, ws_pd, ws_pv);

        k_pass2<<<dim3(NBLK_), dim3(NTHR_), 0, stream>>>(
            hidden, hebb, h2o_w, h2o_b, h2v_b, h2da_b,
            hactiv, activout, valueout, hebb_new, ws_pd, ws_pv);
    } else if (ws_size >= part_bytes) {
        float* ws_pd = (float*)d_ws;                    // [128*8]
        float* ws_pv = ws_pd + B_ * 8;                  // [128*8]

        k_pass1_full<<<dim3(NBLK_), dim3(NTHR_), 0, stream>>>(
            inputs, hidden, hebb, i2h_w, i2h_b, w, alpha,
            h2v_w, h2da_w, hactiv, ws_pd, ws_pv);

        k_pass2<<<dim3(NBLK_), dim3(NTHR_), 0, stream>>>(
            hidden, hebb, h2o_w, h2o_b, h2v_b, h2da_b,
            hactiv, activout, valueout, hebb_new, ws_pd, ws_pv);
    } else {
        float* da = (float*)d_ws;                       // [128] scratch
        k1_hactiv<<<dim3(1024), dim3(256), 0, stream>>>(
            inputs, hidden, hebb, i2h_w, i2h_b, w, alpha, hactiv);
        k2_heads<<<dim3(B_), dim3(256), 0, stream>>>(
            hactiv, h2o_w, h2o_b, h2v_w, h2v_b, h2da_w, h2da_b,
            activout, valueout, da);
        k3_hebb<<<dim3(8192), dim3(256), 0, stream>>>(
            hebb, hidden, hactiv, da, hebb_new);
    }
}

// Round 9
// 286.273 us; speedup vs baseline: 1.1418x; 1.1418x over previous
//
#include <hip/hip_runtime.h>
#include <cstddef>
#include <cstdint>

// Problem constants (all powers of two).
#define B_    128
#define IN_   256
#define OUT_  256
#define HS_   512

#define NTHR_  512
#define NBLK_  1024   // 8 sibling blocks per sample, 64 rows each

// ---------------------------------------------------------------------------
// ROUND 9 = exact revert to the round-6 optimum (285.5 µs, best measured).
// Lessons encoded:
//  - 14 loads/iter in pass1 is deliberate: the 6 "redundant" w/alpha/i2h
//    loads are L2-resident (shared params, 2.5 MB) and double the in-flight
//    bytes per wave. Slimming them (round 8) cost 41 µs.
//  - Deferred/batched reductions (round 7) are neutral: the compiler already
//    pipelines the rolled loop; do not restructure.
//  - 1024x512, launch_bounds(512,4) -> 64 VGPR, 4 blocks/CU, 32 waves/CU.
//  - Kernel boundary (not atomics/grid.sync) publishes the da partials.
//  - Pass-2 hebb re-read hits L3 (134 MB < 256 MB); hebb_new via NT stores.
// ---------------------------------------------------------------------------

__device__ __forceinline__ float clip1(float x) {
    return fminf(fmaxf(x, -1.f), 1.f);
}

typedef float f32x4 __attribute__((ext_vector_type(4)));
__device__ __forceinline__ void nt_store4(float4* p, float4 v) {
    __builtin_nontemporal_store(*(f32x4*)&v, (f32x4*)p);
}

// ---------------------------------------------------------------------------
// Pass 1: hactiv + da/value partials. 1024 blocks x 512 threads.
// ---------------------------------------------------------------------------
__global__ __launch_bounds__(NTHR_, 4) void k_pass1(
    const float* __restrict__ inputs,   // [B, IN]
    const float* __restrict__ hidden,   // [B, HS]
    const float* __restrict__ hebb,     // [B, HS, HS]
    const float* __restrict__ i2h_w,    // [HS, IN]
    const float* __restrict__ i2h_b,    // [HS]
    const float* __restrict__ w,        // [HS, HS]
    const float* __restrict__ alpha,    // [HS, HS]
    const float* __restrict__ h2v_w,    // [HS]
    const float* __restrict__ h2da_w,   // [HS]
    float* __restrict__ hactiv,         // [B, HS]
    float* __restrict__ ws_pd,          // [B*8] da partials (plain stores)
    float* __restrict__ ws_pv)          // [B*8] value partials
{
    const int blk  = blockIdx.x;
    const int b    = blk >> 3;          // sample
    const int s    = blk & 7;           // sibling 0..7
    const int tid  = threadIdx.x;
    const int wave = tid >> 6;          // 0..7
    const int lane = tid & 63;
    const int r0   = s * 64 + wave * 8; // first row of this wave

    __shared__ float s_pd[8], s_pv[8];

    // Lane-fixed per-sample operands.
    const float4* hid4 = (const float4*)(hidden + (size_t)b * HS_);
    const float4 h0  = hid4[lane];
    const float4 h1  = hid4[lane + 64];
    const float4 in4 = ((const float4*)(inputs + (size_t)b * IN_))[lane];

    const float4* hb4 = (const float4*)hebb + ((size_t)b * HS_) * (HS_ / 4);
    const float4* w4  = (const float4*)w;
    const float4* a4  = (const float4*)alpha;
    const float4* iw4 = (const float4*)i2h_w;

    float pd = 0.f, pv = 0.f;
    for (int t = 0; t < 8; t += 2) {
        const int i = r0 + t;
        const float4* hpA = hb4 + (size_t)i * (HS_ / 4);
        const float4* hpB = hpA + (HS_ / 4);
        const float4* wpA = w4  + (size_t)i * (HS_ / 4);
        const float4* apA = a4  + (size_t)i * (HS_ / 4);
        const float4* ipA = iw4 + (size_t)i * (IN_ / 4);

        // 14 independent float4 loads (kept in flight; see header note)
        const float4 xA0 = hpA[lane],            xA1 = hpA[lane + 64];
        const float4 xB0 = hpB[lane],            xB1 = hpB[lane + 64];
        const float4 wA0 = wpA[lane],            wA1 = wpA[lane + 64];
        const float4 wB0 = wpA[128 + lane],      wB1 = wpA[128 + lane + 64];
        const float4 aA0 = apA[lane],            aA1 = apA[lane + 64];
        const float4 aB0 = apA[128 + lane],      aB1 = apA[128 + lane + 64];
        const float4 iA  = ipA[lane];
        const float4 iB  = ipA[64 + lane];

        float a, c;
        a  = (wA0.x + aA0.x * xA0.x) * h0.x;
        a += (wA0.y + aA0.y * xA0.y) * h0.y;
        a += (wA0.z + aA0.z * xA0.z) * h0.z;
        a += (wA0.w + aA0.w * xA0.w) * h0.w;
        a += (wA1.x + aA1.x * xA1.x) * h1.x;
        a += (wA1.y + aA1.y * xA1.y) * h1.y;
        a += (wA1.z + aA1.z * xA1.z) * h1.z;
        a += (wA1.w + aA1.w * xA1.w) * h1.w;
        a += iA.x * in4.x + iA.y * in4.y + iA.z * in4.z + iA.w * in4.w;

        c  = (wB0.x + aB0.x * xB0.x) * h0.x;
        c += (wB0.y + aB0.y * xB0.y) * h0.y;
        c += (wB0.z + aB0.z * xB0.z) * h0.z;
        c += (wB0.w + aB0.w * xB0.w) * h0.w;
        c += (wB1.x + aB1.x * xB1.x) * h1.x;
        c += (wB1.y + aB1.y * xB1.y) * h1.y;
        c += (wB1.z + aB1.z * xB1.z) * h1.z;
        c += (wB1.w + aB1.w * xB1.w) * h1.w;
        c += iB.x * in4.x + iB.y * in4.y + iB.z * in4.z + iB.w * in4.w;

        // two independent 6-step butterflies (chains overlap)
        #pragma unroll
        for (int off = 1; off < 64; off <<= 1) {
            a += __shfl_xor(a, off, 64);
            c += __shfl_xor(c, off, 64);
        }

        const float hA = tanhf(a + i2h_b[i]);
        const float hB = tanhf(c + i2h_b[i + 1]);
        if (lane == 0) {
            float2* hp = (float2*)(hactiv + (size_t)b * HS_ + i);
            *hp = make_float2(hA, hB);
            pd += hA * h2da_w[i] + hB * h2da_w[i + 1];
            pv += hA * h2v_w[i]  + hB * h2v_w[i + 1];
        }
    }

    if (lane == 0) { s_pd[wave] = pd; s_pv[wave] = pv; }
    __syncthreads();
    if (tid == 0) {
        float sd = 0.f, sv = 0.f;
        #pragma unroll
        for (int k = 0; k < 8; ++k) { sd += s_pd[k]; sv += s_pv[k]; }
        ws_pd[b * 8 + s] = sd;      // plain store; kernel boundary = sync
        ws_pv[b * 8 + s] = sv;
    }
}

// ---------------------------------------------------------------------------
// Pass 2: finalize da, hebb update (L3 re-read + NT write), heads.
// ---------------------------------------------------------------------------
__global__ __launch_bounds__(NTHR_, 4) void k_pass2(
    const float* __restrict__ hidden,   // [B, HS]
    const float* __restrict__ hebb,     // [B, HS, HS]
    const float* __restrict__ h2o_w,    // [OUT, HS]
    const float* __restrict__ h2o_b,    // [OUT]
    const float* __restrict__ h2v_b,    // [1]
    const float* __restrict__ h2da_b,   // [1]
    const float* __restrict__ hactiv,   // [B, HS]
    float* __restrict__ activout,       // [B, OUT]
    float* __restrict__ valueout,       // [B]
    float* __restrict__ hebb_new,       // [B, HS, HS]
    const float* __restrict__ ws_pd,    // [B*8]
    const float* __restrict__ ws_pv)    // [B*8]
{
    const int blk  = blockIdx.x;
    const int b    = blk >> 3;
    const int s    = blk & 7;
    const int tid  = threadIdx.x;
    const int wave = tid >> 6;
    const int lane = tid & 63;
    const int r0   = s * 64 + wave * 8;

    __shared__ float s_h[HS_];          // full hactiv[b]
    __shared__ float s_part[512];
    __shared__ float s_bc[1];           // da broadcast

    if (tid < 128)
        ((float4*)s_h)[tid] = ((const float4*)(hactiv + (size_t)b * HS_))[tid];
    if (tid == 0) {
        float sd = 0.f, sv = 0.f;
        #pragma unroll
        for (int k = 0; k < 8; ++k) {
            sd += ws_pd[b * 8 + k];
            sv += ws_pv[b * 8 + k];
        }
        s_bc[0] = tanhf(sd + h2da_b[0]);
        if (s == 0)
            valueout[b] = sv + h2v_b[0];
    }
    __syncthreads();
    const float da_b = s_bc[0];

    // Lane-fixed per-sample operand.
    const float4* hid4 = (const float4*)(hidden + (size_t)b * HS_);
    const float4 h0 = hid4[lane];
    const float4 h1 = hid4[lane + 64];

    const float4* hb4 = (const float4*)hebb + ((size_t)b * HS_) * (HS_ / 4);

    for (int t = 0; t < 8; t += 2) {
        const int i = r0 + t;
        const float4* xp = hb4 + (size_t)i * (HS_ / 4);
        const float4 x0 = xp[lane],       x1 = xp[lane + 64];
        const float4 y0 = xp[128 + lane], y1 = xp[128 + lane + 64];
        const float scA = da_b * s_h[i];
        const float scB = da_b * s_h[i + 1];

        float4 o0, o1, p0, p1;
        o0.x = clip1(fmaf(scA, h0.x, x0.x));
        o0.y = clip1(fmaf(scA, h0.y, x0.y));
        o0.z = clip1(fmaf(scA, h0.z, x0.z));
        o0.w = clip1(fmaf(scA, h0.w, x0.w));
        o1.x = clip1(fmaf(scA, h1.x, x1.x));
        o1.y = clip1(fmaf(scA, h1.y, x1.y));
        o1.z = clip1(fmaf(scA, h1.z, x1.z));
        o1.w = clip1(fmaf(scA, h1.w, x1.w));
        p0.x = clip1(fmaf(scB, h0.x, y0.x));
        p0.y = clip1(fmaf(scB, h0.y, y0.y));
        p0.z = clip1(fmaf(scB, h0.z, y0.z));
        p0.w = clip1(fmaf(scB, h0.w, y0.w));
        p1.x = clip1(fmaf(scB, h1.x, y1.x));
        p1.y = clip1(fmaf(scB, h1.y, y1.y));
        p1.z = clip1(fmaf(scB, h1.z, y1.z));
        p1.w = clip1(fmaf(scB, h1.w, y1.w));

        float4* dp = (float4*)hebb_new + ((size_t)b * HS_ + i) * (HS_ / 4);
        nt_store4(dp + lane,            o0);
        nt_store4(dp + lane + 64,       o1);
        nt_store4(dp + 128 + lane,      p0);
        nt_store4(dp + 128 + lane + 64, p1);
    }

    // ---- head: this block computes its 32 of the 256 outputs -------------
    {
        const int ol = tid & 31;
        const int sg = tid >> 5;            // 0..15 dot-segment
        const int o  = s * 32 + ol;
        const float4* wp  = (const float4*)(h2o_w + (size_t)o * HS_);
        const float4* hp4 = (const float4*)s_h;
        float acc = 0.f;
        #pragma unroll
        for (int c2 = 0; c2 < 8; ++c2) {
            const float4 wv = wp[sg * 8 + c2];
            const float4 hv = hp4[sg * 8 + c2];
            acc += wv.x * hv.x + wv.y * hv.y + wv.z * hv.z + wv.w * hv.w;
        }
        s_part[sg * 32 + ol] = acc;
    }
    __syncthreads();
    if (tid < 32) {
        const int o = s * 32 + tid;
        float acc = h2o_b[o];
        #pragma unroll
        for (int k = 0; k < 16; ++k)
            acc += s_part[k * 32 + tid];
        activout[(size_t)b * OUT_ + o] = acc;
    }
}

// ---------------------------------------------------------------------------
// Fallback path (original verified 3-kernel version) — used only if the
// workspace is too small for the 8 KB of partials.
// ---------------------------------------------------------------------------
__global__ __launch_bounds__(256) void k1_hactiv(
    const float* __restrict__ inputs, const float* __restrict__ hidden,
    const float* __restrict__ hebb, const float* __restrict__ i2h_w,
    const float* __restrict__ i2h_b, const float* __restrict__ w,
    const float* __restrict__ alpha, float* __restrict__ hactiv)
{
    const int b     = blockIdx.x & (B_ - 1);
    const int chunk = blockIdx.x >> 7;
    const int tid   = threadIdx.x;
    const int wave  = tid >> 6;
    const int lane  = tid & 63;

    const float4* hid4 = (const float4*)(hidden + (size_t)b * HS_);
    const float4  h0   = hid4[lane];
    const float4  h1   = hid4[lane + 64];
    const float4  in4  = ((const float4*)(inputs + (size_t)b * IN_))[lane];

    const int i0 = chunk * 64 + wave * 16;

    for (int r = 0; r < 16; ++r) {
        const int i = i0 + r;
        const float4* hb = (const float4*)(hebb + ((size_t)b * HS_ + i) * HS_);
        const float4* wr = (const float4*)(w     + (size_t)i * HS_);
        const float4* ar = (const float4*)(alpha + (size_t)i * HS_);

        const float4 hb0 = hb[lane];
        const float4 hb1 = hb[lane + 64];
        const float4 wv0 = wr[lane];
        const float4 wv1 = wr[lane + 64];
        const float4 av0 = ar[lane];
        const float4 av1 = ar[lane + 64];
        const float4 iw  = ((const float4*)(i2h_w + (size_t)i * IN_))[lane];

        float acc;
        acc  = (wv0.x + av0.x * hb0.x) * h0.x;
        acc += (wv0.y + av0.y * hb0.y) * h0.y;
        acc += (wv0.z + av0.z * hb0.z) * h0.z;
        acc += (wv0.w + av0.w * hb0.w) * h0.w;
        acc += (wv1.x + av1.x * hb1.x) * h1.x;
        acc += (wv1.y + av1.y * hb1.y) * h1.y;
        acc += (wv1.z + av1.z * hb1.z) * h1.z;
        acc += (wv1.w + av1.w * hb1.w) * h1.w;
        acc += iw.x * in4.x + iw.y * in4.y + iw.z * in4.z + iw.w * in4.w;

        #pragma unroll
        for (int off = 32; off > 0; off >>= 1)
            acc += __shfl_down(acc, off, 64);

        if (lane == 0)
            hactiv[(size_t)b * HS_ + i] = tanhf(acc + i2h_b[i]);
    }
}

__global__ __launch_bounds__(256) void k2_heads(
    const float* __restrict__ hactiv, const float* __restrict__ h2o_w,
    const float* __restrict__ h2o_b, const float* __restrict__ h2v_w,
    const float* __restrict__ h2v_b, const float* __restrict__ h2da_w,
    const float* __restrict__ h2da_b, float* __restrict__ activout,
    float* __restrict__ valueout, float* __restrict__ da)
{
    const int b   = blockIdx.x;
    const int tid = threadIdx.x;

    __shared__ float s_h[HS_];
    __shared__ float red_v[256];
    __shared__ float red_d[256];

    for (int t = tid; t < HS_; t += 256)
        s_h[t] = hactiv[(size_t)b * HS_ + t];
    __syncthreads();

    const float4* wr  = (const float4*)(h2o_w + (size_t)tid * HS_);
    const float4* sh4 = (const float4*)s_h;
    float acc = 0.f;
    #pragma unroll 4
    for (int q = 0; q < HS_ / 4; ++q) {
        const float4 wv = wr[q];
        const float4 hv = sh4[q];
        acc += wv.x * hv.x + wv.y * hv.y + wv.z * hv.z + wv.w * hv.w;
    }
    activout[(size_t)b * OUT_ + tid] = acc + h2o_b[tid];

    float pv = 0.f, pd = 0.f;
    for (int t = tid; t < HS_; t += 256) {
        const float hv = s_h[t];
        pv += hv * h2v_w[t];
        pd += hv * h2da_w[t];
    }
    red_v[tid] = pv;
    red_d[tid] = pd;
    __syncthreads();
    for (int s2 = 128; s2 > 0; s2 >>= 1) {
        if (tid < s2) {
            red_v[tid] += red_v[tid + s2];
            red_d[tid] += red_d[tid + s2];
        }
        __syncthreads();
    }
    if (tid == 0) {
        valueout[b] = red_v[0] + h2v_b[0];
        da[b]       = tanhf(red_d[0] + h2da_b[0]);
    }
}

__global__ __launch_bounds__(256) void k3_hebb(
    const float* __restrict__ hebb, const float* __restrict__ hidden,
    const float* __restrict__ hactiv, const float* __restrict__ da,
    float* __restrict__ hebb_new)
{
    const int tid = threadIdx.x;
    const size_t base = (size_t)blockIdx.x * 1024;

    #pragma unroll
    for (int k = 0; k < 4; ++k) {
        const size_t idx = base + (size_t)k * 256 + tid;
        const int j4  = (int)(idx & 127);
        const int row = (int)(idx >> 7);
        const int i   = row & (HS_ - 1);
        const int b   = row >> 9;

        const float scale = da[b] * hactiv[(size_t)b * HS_ + i];
        const float4 hv = ((const float4*)hebb)[idx];
        const float4 hd = ((const float4*)hidden)[(size_t)b * (HS_ / 4) + j4];

        float4 r;
        r.x = fminf(fmaxf(fmaf(scale, hd.x, hv.x), -1.f), 1.f);
        r.y = fminf(fmaxf(fmaf(scale, hd.y, hv.y), -1.f), 1.f);
        r.z = fminf(fmaxf(fmaf(scale, hd.z, hv.z), -1.f), 1.f);
        r.w = fminf(fmaxf(fmaf(scale, hd.w, hv.w), -1.f), 1.f);
        ((float4*)hebb_new)[idx] = r;
    }
}

// ---------------------------------------------------------------------------
extern "C" void kernel_launch(void* const* d_in, const int* in_sizes, int n_in,
                              void* d_out, int out_size, void* d_ws, size_t ws_size,
                              hipStream_t stream)
{
    const float* inputs = (const float*)d_in[0];
    const float* hidden = (const float*)d_in[1];
    const float* hebb   = (const float*)d_in[2];
    const float* i2h_w  = (const float*)d_in[3];
    const float* i2h_b  = (const float*)d_in[4];
    const float* w      = (const float*)d_in[5];
    const float* alpha  = (const float*)d_in[6];
    const float* h2o_w  = (const float*)d_in[7];
    const float* h2o_b  = (const float*)d_in[8];
    const float* h2v_w  = (const float*)d_in[9];
    const float* h2v_b  = (const float*)d_in[10];
    const float* h2da_w = (const float*)d_in[11];
    const float* h2da_b = (const float*)d_in[12];

    float* out = (float*)d_out;
    // Output layout (flat, return order): activout | valueout | hactiv | hebb_new
    float* activout = out;                              // 128*256   = 32768
    float* valueout = out + 32768;                      // 128
    float* hactiv   = out + 32768 + 128;                // 128*512   = 65536
    float* hebb_new = out + 32768 + 128 + 65536;        // 128*512*512

    const size_t part_bytes = (size_t)(2 * B_ * 8) * sizeof(float);   // 8 KB

    if (ws_size >= part_bytes) {
        float* ws_pd = (float*)d_ws;                    // [128*8]
        float* ws_pv = ws_pd + B_ * 8;                  // [128*8]

        k_pass1<<<dim3(NBLK_), dim3(NTHR_), 0, stream>>>(
            inputs, hidden, hebb, i2h_w, i2h_b, w, alpha,
            h2v_w, h2da_w, hactiv, ws_pd, ws_pv);

        k_pass2<<<dim3(NBLK_), dim3(NTHR_), 0, stream>>>(
            hidden, hebb, h2o_w, h2o_b, h2v_b, h2da_b,
            hactiv, activout, valueout, hebb_new, ws_pd, ws_pv);
    } else {
        float* da = (float*)d_ws;                       // [128] scratch
        k1_hactiv<<<dim3(1024), dim3(256), 0, stream>>>(
            inputs, hidden, hebb, i2h_w, i2h_b, w, alpha, hactiv);
        k2_heads<<<dim3(B_), dim3(256), 0, stream>>>(
            hactiv, h2o_w, h2o_b, h2v_w, h2v_b, h2da_w, h2da_b,
            activout, valueout, da);
        k3_hebb<<<dim3(8192), dim3(256), 0, stream>>>(
            hebb, hidden, hactiv, da, hebb_new);
    }
}